// Round 4
// baseline (154.584 us; speedup 1.0000x reference)
//
#include <hip/hip_runtime.h>
#include <math.h>

#define B 8
#define H 384
#define W 384
#define HW (H*W)
#define NTOT (B*HW)
#define INF_I 10000
#define NFB 192            // fused-reduction blocks in launch 1
#define NVB 48             // vertical-EDT blocks in launch 1
#define NROW (B*H)         // 3072 row blocks in launch 2

// ws layout (bytes):
//   counter @ 0       : unsigned (k_row completion count)
//   part2   @ 512     : NFB*25 doubles (38400 B)  fused partials
//   part    @ 38912   : NROW doubles   (24576 B)  row partials
//   g2u     @ 63488   : NTOT uint      (dpos | dneg<<16)
//   sumA    @ 4782080 : HW float       (sum_b |p - t|)

// ---------------- launch 1: fused BCE/dice/sumA + vertical EDT ----------------
__global__ __launch_bounds__(768) void k_stage1(const float* __restrict__ pred,
                                                const int* __restrict__ tgt,
                                                float* __restrict__ sumA,
                                                double* __restrict__ part2,
                                                unsigned* __restrict__ g2u,
                                                unsigned* __restrict__ counter) {
    __shared__ float lds[12][25];
    __shared__ unsigned bmsh[12][64];
    int tid = threadIdx.x;

    if (blockIdx.x < NFB) {
        // ---- fused BCE + dice partials + sumA: one pixel/thread, 8 batches ----
        if (blockIdx.x == 0 && tid == 0) *counter = 0u;
        int pix = blockIdx.x * 768 + tid;
        float vals[25];                    // 0=bce, 1+b=p, 9+b=p*t, 17+b=t
        float sA = 0.f, bce = 0.f;
#pragma unroll
        for (int b = 0; b < 8; ++b) {
            float x = pred[b * HW + pix];
            int t = tgt[b * HW + pix];
            float e = expf(-fabsf(x));
            float r = 1.f / (1.f + e);
            float p = (x >= 0.f) ? r : 1.f - r;                // stable sigmoid
            bce += fmaxf(x, 0.f) + log1pf(e) - x * (float)t;   // softplus - x*t
            vals[1 + b] = p;
            vals[9 + b] = t ? p : 0.f;
            vals[17 + b] = (float)t;
            sA += t ? 1.f - p : p;
        }
        sumA[pix] = sA;
        vals[0] = bce;
#pragma unroll
        for (int k = 0; k < 25; ++k)
#pragma unroll
            for (int o = 32; o; o >>= 1) vals[k] += __shfl_down(vals[k], o);
        int wave = tid >> 6, lane = tid & 63;
        if (lane == 0)
#pragma unroll
            for (int k = 0; k < 25; ++k) lds[wave][k] = vals[k];
        __syncthreads();
        if (tid < 25) {
            double s = 0.0;
#pragma unroll
            for (int wv = 0; wv < 12; ++wv) s += (double)lds[wv][tid];
            part2[blockIdx.x * 25 + tid] = s;
        }
    } else {
        // ---- vertical distance, word-parallel: thread = (32-row word, column) ----
        int vb = blockIdx.x - NFB;
        int wd = tid >> 6;                 // 0..11
        int wl = tid & 63;
        int b = vb / 6;
        int w = (vb % 6) * 64 + wl;

        const int* colp = tgt + b * HW + w + (wd * 32) * W;
        unsigned m = 0;
#pragma unroll
        for (int i = 0; i < 32; ++i)
            m |= (colp[i * W] != 0) ? (1u << i) : 0u;
        bmsh[wd][wl] = m;
        __syncthreads();

        unsigned mp = m, mn = ~m;
        int dfe_p = INF_I, dfe_n = INF_I, dbe_p = INF_I, dbe_n = INF_I;
        if (wd > 0) {
            int k = wd - 1; unsigned mm;
            while ((mm = bmsh[k][wl]) == 0 && k > 0) --k;
            if (mm) dfe_p = wd * 32 - 1 - (k * 32 + 31 - __clz(mm));
            k = wd - 1;
            while ((mm = ~bmsh[k][wl]) == 0 && k > 0) --k;
            if (mm) dfe_n = wd * 32 - 1 - (k * 32 + 31 - __clz(mm));
        }
        if (wd < 11) {
            int k = wd + 1; unsigned mm;
            while ((mm = bmsh[k][wl]) == 0 && k < 11) ++k;
            if (mm) dbe_p = k * 32 + (__ffs(mm) - 1) - (wd + 1) * 32;
            k = wd + 1;
            while ((mm = ~bmsh[k][wl]) == 0 && k < 11) ++k;
            if (mm) dbe_n = k * 32 + (__ffs(mm) - 1) - (wd + 1) * 32;
        }

        int dfp[32], dfn[32];
        int cp = dfe_p, cn = dfe_n;
#pragma unroll
        for (int i = 0; i < 32; ++i) {
            cp = ((mp >> i) & 1u) ? 0 : min(cp + 1, INF_I);
            cn = ((mn >> i) & 1u) ? 0 : min(cn + 1, INF_I);
            dfp[i] = cp; dfn[i] = cn;
        }
        unsigned* outc = g2u + b * HW + (wd * 32) * W + w;
        cp = dbe_p; cn = dbe_n;
#pragma unroll
        for (int i = 31; i >= 0; --i) {
            cp = ((mp >> i) & 1u) ? 0 : min(cp + 1, INF_I);
            cn = ((mn >> i) & 1u) ? 0 : min(cn + 1, INF_I);
            int dp = min(dfp[i], cp);
            int dn = min(dfn[i], cn);
            outc[i * W] = (unsigned)dp | ((unsigned)dn << 16);
        }
    }
}

// ---------------- launch 2: windowed row envelope + loss2 dot + final ----------------
__global__ __launch_bounds__(64) void k_row(const unsigned* __restrict__ g2u,
                                            const float* __restrict__ sumA,
                                            double* __restrict__ part,
                                            const double* __restrict__ part2,
                                            unsigned* __restrict__ counter,
                                            float* __restrict__ out) {
    int bh = blockIdx.x;
    int b = bh / H, h = bh % H;
    __shared__ float lfp[W + W/16 + 2], lfn[W + W/16 + 2];   // +1 pad per 16
    const unsigned* row = g2u + b * HW + h * W;
    int tid = threadIdx.x;
    for (int q = tid; q < W; q += 64) {
        unsigned v = row[q];
        float dp = (float)(v & 0xFFFFu);
        float dn = (float)(v >> 16);
        int s = q + (q >> 4);
        lfp[s] = dp * dp;                 // exact: ints <= 1e4 -> d^2 <= 1e8
        lfn[s] = dn * dn;
    }
    __syncthreads();

    int base = 6 * tid - 8;
    float rp[22], rn[22];
#pragma unroll
    for (int r = 0; r < 22; ++r) {
        int j = base + r;
        j = j < 0 ? 0 : (j > W - 1 ? W - 1 : j);
        int s = j + (j >> 4);
        rp[r] = lfp[s];
        rn[r] = lfn[s];
    }
    const float DD[17] = {64.f,49.f,36.f,25.f,16.f,9.f,4.f,1.f,0.f,
                          1.f,4.f,9.f,16.f,25.f,36.f,49.f,64.f};
    float partial = 0.f;
#pragma unroll
    for (int q = 0; q < 6; ++q) {
        int i = 6 * tid + q;
        float Dp = 3.0e38f, Dn = 3.0e38f;
#pragma unroll
        for (int tt = 0; tt < 17; ++tt) {
            Dp = fminf(Dp, rp[q + tt] + DD[tt]);
            Dn = fminf(Dn, rn[q + tt] + DD[tt]);
        }
        if (Dp > 64.f || Dn > 64.f) {     // exactness not proven -> full row
            float fi = (float)i;
            for (int j = 0; j < W; ++j) {
                int s = j + (j >> 4);
                float d = fi - (float)j;
                Dp = fminf(Dp, fmaf(d, d, lfp[s]));
                Dn = fminf(Dn, fmaf(d, d, lfn[s]));
            }
        }
        float sdf = fabsf(sqrtf(Dp) - sqrtf(Dn));
        partial += sdf * sumA[h * W + i];
    }
    double v = partial;
#pragma unroll
    for (int o = 32; o; o >>= 1) v += __shfl_down(v, o);
    if (tid == 0) part[bh] = v;

    // ---- last-block-done final combine (deterministic: fixed read order) ----
    __threadfence();
    __shared__ unsigned done;
    if (tid == 0) done = atomicAdd(counter, 1u);
    __syncthreads();
    if (done == NROW - 1) {
        __threadfence();
        // loss2 total: sum of 3072 row partials
        double s2 = 0.0;
        for (int i = tid; i < NROW; i += 64) s2 += part[i];
#pragma unroll
        for (int o = 32; o; o >>= 1) s2 += __shfl_down(s2, o);
        // fused partials: 25 values x NFB blocks, 2 threads per value
        __shared__ double sval[25];
        if (tid < 50) {
            int vv = tid >> 1, sub = tid & 1;
            double s = 0.0;
            for (int blk = sub; blk < NFB; blk += 2) s += part2[blk * 25 + vv];
            s += __shfl_down(s, 1);
            if (sub == 0) sval[vv] = s;
        }
        __syncthreads();
        if (tid == 0) {
            double bce = sval[0] / (double)NTOT;
            double dsum = 0.0;
            for (int bb = 0; bb < 8; ++bb)
                dsum += (2.0 * sval[9 + bb] + 1e-5) / (sval[1 + bb] + sval[17 + bb] + 1e-5);
            double dice = dsum / 8.0;
            double loss1 = 0.5 * bce + (1.0 - dice);
            double loss2 = s2 / ((double)B * (double)B * (double)HW);
            out[0] = (float)(0.7 * loss1 + 0.03 * loss2);
        }
    }
}

extern "C" void kernel_launch(void* const* d_in, const int* in_sizes, int n_in,
                              void* d_out, int out_size, void* d_ws, size_t ws_size,
                              hipStream_t stream) {
    const float* pred = (const float*)d_in[0];
    const int* tgt = (const int*)d_in[1];
    float* out = (float*)d_out;
    char* ws = (char*)d_ws;
    unsigned* counter = (unsigned*)ws;
    double* part2 = (double*)(ws + 512);
    double* part = (double*)(ws + 38912);
    unsigned* g2u = (unsigned*)(ws + 63488);
    float* sumA = (float*)(ws + 4782080);

    k_stage1<<<NFB + NVB, 768, 0, stream>>>(pred, tgt, sumA, part2, g2u, counter);
    k_row<<<NROW, 64, 0, stream>>>(g2u, sumA, part, part2, counter, out);
}

// Round 5
// 35.336 us; speedup vs baseline: 4.3747x; 4.3747x over previous
//
#include <hip/hip_runtime.h>
#include <math.h>

#define B 8
#define H 384
#define W 384
#define HW (H*W)
#define NTOT (B*HW)
#define INF_I 10000
#define NFB 192            // fused-reduction blocks in stage1
#define NVB 48             // vertical-EDT blocks in stage1
#define NROW (B*H)         // 3072 row blocks

// ws layout (bytes):
//   part2 @ 0       : NFB*25 doubles (38400 B)  fused partials
//   part  @ 38912   : NROW doubles   (24576 B)  row partials
//   g2u   @ 63488   : NTOT uint      (dpos | dneg<<16)
//   sumA  @ 4782080 : HW float       (sum_b |p - t|)

// ---------------- launch 1: fused BCE/dice/sumA + vertical EDT ----------------
__global__ __launch_bounds__(768) void k_stage1(const float* __restrict__ pred,
                                                const int* __restrict__ tgt,
                                                float* __restrict__ sumA,
                                                double* __restrict__ part2,
                                                unsigned* __restrict__ g2u) {
    __shared__ float lds[12][25];
    __shared__ unsigned bmsh[12][64];
    int tid = threadIdx.x;

    if (blockIdx.x < NFB) {
        // ---- fused BCE + dice partials + sumA: one pixel/thread, 8 batches ----
        int pix = blockIdx.x * 768 + tid;
        float vals[25];                    // 0=bce, 1+b=p, 9+b=p*t, 17+b=t
        float sA = 0.f, bce = 0.f;
#pragma unroll
        for (int b = 0; b < 8; ++b) {
            float x = pred[b * HW + pix];
            int t = tgt[b * HW + pix];
            float e = expf(-fabsf(x));
            float r = 1.f / (1.f + e);
            float p = (x >= 0.f) ? r : 1.f - r;                // stable sigmoid
            bce += fmaxf(x, 0.f) + log1pf(e) - x * (float)t;   // softplus - x*t
            vals[1 + b] = p;
            vals[9 + b] = t ? p : 0.f;
            vals[17 + b] = (float)t;
            sA += t ? 1.f - p : p;
        }
        sumA[pix] = sA;
        vals[0] = bce;
#pragma unroll
        for (int k = 0; k < 25; ++k)
#pragma unroll
            for (int o = 32; o; o >>= 1) vals[k] += __shfl_down(vals[k], o);
        int wave = tid >> 6, lane = tid & 63;
        if (lane == 0)
#pragma unroll
            for (int k = 0; k < 25; ++k) lds[wave][k] = vals[k];
        __syncthreads();
        if (tid < 25) {
            double s = 0.0;
#pragma unroll
            for (int wv = 0; wv < 12; ++wv) s += (double)lds[wv][tid];
            part2[blockIdx.x * 25 + tid] = s;
        }
    } else {
        // ---- vertical distance, word-parallel: thread = (32-row word, column) ----
        int vb = blockIdx.x - NFB;
        int wd = tid >> 6;                 // 0..11
        int wl = tid & 63;
        int b = vb / 6;
        int w = (vb % 6) * 64 + wl;

        const int* colp = tgt + b * HW + w + (wd * 32) * W;
        unsigned m = 0;
#pragma unroll
        for (int i = 0; i < 32; ++i)
            m |= (colp[i * W] != 0) ? (1u << i) : 0u;
        bmsh[wd][wl] = m;
        __syncthreads();

        unsigned mp = m, mn = ~m;
        int dfe_p = INF_I, dfe_n = INF_I, dbe_p = INF_I, dbe_n = INF_I;
        if (wd > 0) {
            int k = wd - 1; unsigned mm;
            while ((mm = bmsh[k][wl]) == 0 && k > 0) --k;
            if (mm) dfe_p = wd * 32 - 1 - (k * 32 + 31 - __clz(mm));
            k = wd - 1;
            while ((mm = ~bmsh[k][wl]) == 0 && k > 0) --k;
            if (mm) dfe_n = wd * 32 - 1 - (k * 32 + 31 - __clz(mm));
        }
        if (wd < 11) {
            int k = wd + 1; unsigned mm;
            while ((mm = bmsh[k][wl]) == 0 && k < 11) ++k;
            if (mm) dbe_p = k * 32 + (__ffs(mm) - 1) - (wd + 1) * 32;
            k = wd + 1;
            while ((mm = ~bmsh[k][wl]) == 0 && k < 11) ++k;
            if (mm) dbe_n = k * 32 + (__ffs(mm) - 1) - (wd + 1) * 32;
        }

        int dfp[32], dfn[32];
        int cp = dfe_p, cn = dfe_n;
#pragma unroll
        for (int i = 0; i < 32; ++i) {
            cp = ((mp >> i) & 1u) ? 0 : min(cp + 1, INF_I);
            cn = ((mn >> i) & 1u) ? 0 : min(cn + 1, INF_I);
            dfp[i] = cp; dfn[i] = cn;
        }
        unsigned* outc = g2u + b * HW + (wd * 32) * W + w;
        cp = dbe_p; cn = dbe_n;
#pragma unroll
        for (int i = 31; i >= 0; --i) {
            cp = ((mp >> i) & 1u) ? 0 : min(cp + 1, INF_I);
            cn = ((mn >> i) & 1u) ? 0 : min(cn + 1, INF_I);
            int dp = min(dfp[i], cp);
            int dn = min(dfn[i], cn);
            outc[i * W] = (unsigned)dp | ((unsigned)dn << 16);
        }
    }
}

// ---------------- launch 2: windowed row envelope + loss2 dot ----------------
__global__ __launch_bounds__(64) void k_row(const unsigned* __restrict__ g2u,
                                            const float* __restrict__ sumA,
                                            double* __restrict__ part) {
    int bh = blockIdx.x;
    int b = bh / H, h = bh % H;
    __shared__ float lfp[W + W/16 + 2], lfn[W + W/16 + 2];   // +1 pad per 16
    const unsigned* row = g2u + b * HW + h * W;
    int tid = threadIdx.x;
    for (int q = tid; q < W; q += 64) {
        unsigned v = row[q];
        float dp = (float)(v & 0xFFFFu);
        float dn = (float)(v >> 16);
        int s = q + (q >> 4);
        lfp[s] = dp * dp;                 // exact: ints <= 1e4 -> d^2 <= 1e8
        lfn[s] = dn * dn;
    }
    __syncthreads();

    int base = 6 * tid - 8;
    float rp[22], rn[22];
#pragma unroll
    for (int r = 0; r < 22; ++r) {
        int j = base + r;
        j = j < 0 ? 0 : (j > W - 1 ? W - 1 : j);
        int s = j + (j >> 4);
        rp[r] = lfp[s];
        rn[r] = lfn[s];
    }
    const float DD[17] = {64.f,49.f,36.f,25.f,16.f,9.f,4.f,1.f,0.f,
                          1.f,4.f,9.f,16.f,25.f,36.f,49.f,64.f};
    float partial = 0.f;
#pragma unroll
    for (int q = 0; q < 6; ++q) {
        int i = 6 * tid + q;
        float Dp = 3.0e38f, Dn = 3.0e38f;
#pragma unroll
        for (int tt = 0; tt < 17; ++tt) {
            Dp = fminf(Dp, rp[q + tt] + DD[tt]);
            Dn = fminf(Dn, rn[q + tt] + DD[tt]);
        }
        if (Dp > 64.f || Dn > 64.f) {     // exactness not proven -> full row
            float fi = (float)i;
            for (int j = 0; j < W; ++j) {
                int s = j + (j >> 4);
                float d = fi - (float)j;
                Dp = fminf(Dp, fmaf(d, d, lfp[s]));
                Dn = fminf(Dn, fmaf(d, d, lfn[s]));
            }
        }
        float sdf = fabsf(sqrtf(Dp) - sqrtf(Dn));
        partial += sdf * sumA[h * W + i];
    }
    double v = partial;
#pragma unroll
    for (int o = 32; o; o >>= 1) v += __shfl_down(v, o);
    if (tid == 0) part[bh] = v;
}

// ---------------- launch 3: final reduction + combine ----------------
__global__ __launch_bounds__(256) void k_final(const double* __restrict__ part2,
                                               const double* __restrict__ part,
                                               float* __restrict__ out) {
    __shared__ double sval[25];
    __shared__ double sl2[4];
    int tid = threadIdx.x;
    if (tid < 200) {
        int v = tid >> 3, sub = tid & 7;
        double s = 0.0;
        for (int blk = sub; blk < NFB; blk += 8) s += part2[blk * 25 + v];
#pragma unroll
        for (int o = 4; o; o >>= 1) s += __shfl_down(s, o);
        if (sub == 0) sval[v] = s;
    }
    double s2 = 0.0;
    for (int i = tid; i < NROW; i += 256) s2 += part[i];
#pragma unroll
    for (int o = 32; o; o >>= 1) s2 += __shfl_down(s2, o);
    if ((tid & 63) == 0) sl2[tid >> 6] = s2;
    __syncthreads();
    if (tid == 0) {
        double bce = sval[0] / (double)NTOT;
        double dsum = 0.0;
        for (int b = 0; b < 8; ++b)
            dsum += (2.0 * sval[9 + b] + 1e-5) / (sval[1 + b] + sval[17 + b] + 1e-5);
        double dice = dsum / 8.0;
        double loss1 = 0.5 * bce + (1.0 - dice);
        double loss2 = (sl2[0] + sl2[1] + sl2[2] + sl2[3])
                     / ((double)B * (double)B * (double)HW);
        out[0] = (float)(0.7 * loss1 + 0.03 * loss2);
    }
}

extern "C" void kernel_launch(void* const* d_in, const int* in_sizes, int n_in,
                              void* d_out, int out_size, void* d_ws, size_t ws_size,
                              hipStream_t stream) {
    const float* pred = (const float*)d_in[0];
    const int* tgt = (const int*)d_in[1];
    float* out = (float*)d_out;
    char* ws = (char*)d_ws;
    double* part2 = (double*)ws;
    double* part = (double*)(ws + 38912);
    unsigned* g2u = (unsigned*)(ws + 63488);
    float* sumA = (float*)(ws + 4782080);

    k_stage1<<<NFB + NVB, 768, 0, stream>>>(pred, tgt, sumA, part2, g2u);
    k_row<<<NROW, 64, 0, stream>>>(g2u, sumA, part);
    k_final<<<1, 256, 0, stream>>>(part2, part, out);
}